// Round 1
// 194.254 us; speedup vs baseline: 1.0166x; 1.0166x over previous
//
#include <hip/hip_runtime.h>

// GCN 2-layer forward for MI355X.
// out = D^-1/2 (A+I) D^-1/2 (X W) + b, twice, relu between.
// R2: CSR gather. R4: g bf16. R5: MFMA split-bf16 GEMM. R6-R8: bucketed CSR build.
// R9: XCD slicing FAILED. R10: scalar-addressed gather. R11: bf16 h2, 2-MFMA gemm2.
// R12: LDS-fused gather+gemm2 FAILED. R13: predicated unroll-8 gather (tail kill).
// R14: dinv deferred out of layer-1 GEMM; merged csr+gemm1 launch; CHUNK 2048.
// R15: gathers rewritten: half-wave(128F)/quarter-wave(64F) per node with 8B row
//      loads (2/4 edges per VMEM instr), srow+dinv loaded once per 32/16-edge
//      window and broadcast per-edge via ds_bpermute (__shfl) -> per-edge VMEM
//      2.0->0.53 / 1.0->0.28; wave-uniform degmax loop (shfl_xor) keeps full
//      exec for shfl. setup merged into scatter launch (gcur memset to 0,
//      counts are zero-based now).

constexpr int KD = 128;      // inner dim of both GEMMs (Fin = Fh = 128)
constexpr int CHUNK = 2048;  // edges per block in scatter pass
constexpr int BCAP = 6144;   // slack capacity per bucket (mean 4096, sigma ~64)

using short8  = __attribute__((ext_vector_type(8))) short;
using float4v = __attribute__((ext_vector_type(4))) float;

// ---------------- bf16 helpers (storage = ushort, math = fp32) ----------------

__device__ __forceinline__ unsigned short f2bf(float f) {
    unsigned int u = __float_as_uint(f);
    u = (u + 0x7fffu + ((u >> 16) & 1u)) >> 16;  // round-to-nearest-even
    return (unsigned short)u;
}

__device__ __forceinline__ float2 bfpair(unsigned int u) {
    float2 f;
    f.x = __uint_as_float(u << 16);          // low short = first feature
    f.y = __uint_as_float(u & 0xffff0000u);  // high short = second feature
    return f;
}

__device__ __forceinline__ unsigned int packbf(float x, float y) {
    return (unsigned int)f2bf(x) | ((unsigned int)f2bf(y) << 16);
}

// split x = hi + lo (both bf16); subtraction is exact, |err| ~ 2^-17 |x|
__device__ __forceinline__ void bfsplit(float x, unsigned short& h, unsigned short& l) {
    h = f2bf(x);
    float fh = __uint_as_float((unsigned int)h << 16);
    l = f2bf(x - fh);
}

// ------- MERGED: bucket_scatter (blocks [0,NBS)) + W transpose (rest) -------
// gcur must be zeroed (hipMemsetAsync) before this launch; counts zero-based.
__global__ __launch_bounds__(256) void scatter_setup(
        const int* __restrict__ row, const int* __restrict__ col,
        int* gcur, unsigned int* __restrict__ bpack, int E, int NBS,
        const float* __restrict__ W1, unsigned short* __restrict__ Wth1,
        unsigned short* __restrict__ Wtl1,
        const float* __restrict__ W2, unsigned short* __restrict__ Wth2,
        unsigned short* __restrict__ Wtl2) {
    __shared__ int lh[256];
    __shared__ int lbase[256];

    if ((int)blockIdx.x >= NBS) {
        // -------- weight transpose + split (96 blocks x 256 = 24576 elems) ----
        int id = ((int)blockIdx.x - NBS) * 256 + threadIdx.x;
        unsigned short h, l;
        if (id < 16384) {                    // W1: [128,128]
            int k = id >> 7, n = id & 127;
            bfsplit(W1[id], h, l);
            Wth1[n * KD + k] = h;
            Wtl1[n * KD + k] = l;
        } else {                             // W2: [128,64]
            int id2 = id - 16384;
            int k = id2 >> 6, n = id2 & 63;
            bfsplit(W2[id2], h, l);
            Wth2[n * KD + k] = h;
            Wtl2[n * KD + k] = l;
        }
        return;
    }

    // -------- edge scatter into slack buckets; record = (row<<16)|col --------
    lh[threadIdx.x] = 0;
    __syncthreads();
    int base = (int)blockIdx.x * CHUNK;
#pragma unroll
    for (int r = 0; r < CHUNK / 256; ++r) {
        int e = base + r * 256 + threadIdx.x;
        if (e < E) atomicAdd(&lh[col[e] >> 8], 1);
    }
    __syncthreads();
    int c0 = lh[threadIdx.x];
    lbase[threadIdx.x] = c0 ? (threadIdx.x * BCAP + atomicAdd(&gcur[threadIdx.x], c0)) : 0;
    __syncthreads();
    lh[threadIdx.x] = 0;  // reuse as local running offset
    __syncthreads();
#pragma unroll
    for (int r = 0; r < CHUNK / 256; ++r) {
        int e = base + r * 256 + threadIdx.x;
        if (e < E) {
            int c = col[e];
            int b = c >> 8;
            int slot = lbase[b] + atomicAdd(&lh[b], 1);
            bpack[slot] = ((unsigned int)row[e] << 16) | (unsigned int)c;
        }
    }
}

// ------- MERGED: bucket_csr (blocks [0,NBUCKET)) + layer-1 GEMM (rest) -------
__global__ __launch_bounds__(256) void csr_and_gemm1(
        const unsigned int* __restrict__ bpack, const int* __restrict__ gcur,
        int* __restrict__ rowptr, float* __restrict__ dinv,
        unsigned short* __restrict__ srow, int N, int E, int NBUCKET,
        const float* __restrict__ X,
        const unsigned short* __restrict__ Wth,
        const unsigned short* __restrict__ Wtl,
        unsigned short* __restrict__ G) {
    __shared__ int s[256];
    __shared__ int lh[256];
    __shared__ int lcur[256];
    __shared__ int sh_bstart;

    if ((int)blockIdx.x < NBUCKET) {
        // ---------------- CSR build ----------------
        int b = blockIdx.x;
        int t = threadIdx.x;
        int cntb = gcur[t];          // zero-based count (R15)
        s[t] = cntb;
        __syncthreads();
        for (int off = 1; off < 256; off <<= 1) {
            int tv = (t >= off) ? s[t - off] : 0;
            __syncthreads();
            s[t] += tv;
            __syncthreads();
        }
        if (t == b) sh_bstart = s[t] - cntb;  // exclusive prefix of this bucket
        if (b == 0 && t == 0) rowptr[N] = E;
        lh[t] = 0;
        __syncthreads();
        int bstart = sh_bstart;
        int nE = gcur[b];
        int base = b * BCAP;
        for (int i = t; i < nE; i += 256)
            atomicAdd(&lh[bpack[base + i] & 255], 1);
        __syncthreads();
        int v = lh[t];
        s[t] = v;
        __syncthreads();
        for (int off = 1; off < 256; off <<= 1) {
            int tv = (t >= off) ? s[t - off] : 0;
            __syncthreads();
            s[t] += tv;
            __syncthreads();
        }
        int myStart = bstart + s[t] - v;  // exclusive
        int node = (b << 8) + t;
        if (node < N) {
            rowptr[node] = myStart;
            dinv[node] = rsqrtf(1.0f + (float)v);
        }
        lcur[t] = myStart;
        __syncthreads();
        for (int i = t; i < nE; i += 256) {
            unsigned int p = bpack[base + i];
            int slot = atomicAdd(&lcur[p & 255], 1);
            srow[slot] = (unsigned short)(p >> 16);
        }
    } else {
        // ---------------- layer-1 GEMM (split-A, 3 MFMAs, no dinv) ----------
        constexpr int FOUT = 128, NT = 8;
        int wave = threadIdx.x >> 6;
        int lane = threadIdx.x & 63;
        int row0 = (((int)blockIdx.x - NBUCKET) * 4 + wave) * 16;
        if (row0 >= N) return;
        int m = lane & 15;
        int quad = lane >> 4;

        float4v acc[NT];
#pragma unroll
        for (int ct = 0; ct < NT; ++ct) acc[ct] = (float4v){0.f, 0.f, 0.f, 0.f};

        const float* xrow = X + (size_t)(row0 + m) * KD + quad * 8;

#pragma unroll
        for (int ks = 0; ks < 4; ++ks) {
            float4 xa = *(const float4*)(xrow + ks * 32);
            float4 xb = *(const float4*)(xrow + ks * 32 + 4);
            float xs[8] = {xa.x, xa.y, xa.z, xa.w, xb.x, xb.y, xb.z, xb.w};
            short8 ah, al;
#pragma unroll
            for (int j = 0; j < 8; ++j) {
                unsigned short h, l;
                bfsplit(xs[j], h, l);
                ah[j] = (short)h;
                al[j] = (short)l;
            }
            int koff = ks * 32 + quad * 8;
#pragma unroll
            for (int ct = 0; ct < NT; ++ct) {
                short8 bh = *(const short8*)(Wth + (size_t)(ct * 16 + m) * KD + koff);
                short8 bl = *(const short8*)(Wtl + (size_t)(ct * 16 + m) * KD + koff);
                acc[ct] = __builtin_amdgcn_mfma_f32_16x16x32_bf16(ah, bh, acc[ct], 0, 0, 0);
                acc[ct] = __builtin_amdgcn_mfma_f32_16x16x32_bf16(al, bh, acc[ct], 0, 0, 0);
                acc[ct] = __builtin_amdgcn_mfma_f32_16x16x32_bf16(ah, bl, acc[ct], 0, 0, 0);
            }
        }

#pragma unroll
        for (int r = 0; r < 4; ++r) {
            int row = row0 + quad * 4 + r;
#pragma unroll
            for (int ct = 0; ct < NT; ++ct) {
                G[(size_t)row * FOUT + ct * 16 + m] = f2bf(acc[ct][r]);
            }
        }
    }
}

// -------- layer-2 GEMM (bf16 in): G = bf16(dinv*(H@W)), 2 MFMAs, no A-split --
__global__ __launch_bounds__(256) void gemm_mfma2(const unsigned short* __restrict__ H,
                                                  const unsigned short* __restrict__ Wth,
                                                  const unsigned short* __restrict__ Wtl,
                                                  const float* __restrict__ dinv,
                                                  unsigned short* __restrict__ G, int N) {
    constexpr int FOUT = 64, NT = 4;
    int wave = threadIdx.x >> 6;
    int lane = threadIdx.x & 63;
    int row0 = (blockIdx.x * 4 + wave) * 16;
    if (row0 >= N) return;
    int m = lane & 15;
    int quad = lane >> 4;

    float4v acc[NT];
#pragma unroll
    for (int ct = 0; ct < NT; ++ct) acc[ct] = (float4v){0.f, 0.f, 0.f, 0.f};

    const unsigned short* hrow = H + (size_t)(row0 + m) * KD + quad * 8;

#pragma unroll
    for (int ks = 0; ks < 4; ++ks) {
        short8 a = *(const short8*)(hrow + ks * 32);
        int koff = ks * 32 + quad * 8;
#pragma unroll
        for (int ct = 0; ct < NT; ++ct) {
            short8 bh = *(const short8*)(Wth + (size_t)(ct * 16 + m) * KD + koff);
            short8 bl = *(const short8*)(Wtl + (size_t)(ct * 16 + m) * KD + koff);
            acc[ct] = __builtin_amdgcn_mfma_f32_16x16x32_bf16(a, bh, acc[ct], 0, 0, 0);
            acc[ct] = __builtin_amdgcn_mfma_f32_16x16x32_bf16(a, bl, acc[ct], 0, 0, 0);
        }
    }

#pragma unroll
    for (int r = 0; r < 4; ++r) {
        int row = row0 + quad * 4 + r;
        float s = dinv[row];
#pragma unroll
        for (int ct = 0; ct < 4; ++ct) {
            G[(size_t)row * FOUT + ct * 16 + m] = f2bf(acc[ct][r] * s);
        }
    }
}

// ---------------- CSR gather + finalize (fused), bf16 operand ----------------
// F=128 (R15): HALF-wave per node, lane loads 8B (dwordx2) -> one row-load
// retires 2 edges. srow window (32 ids) + their dinv loaded ONCE per window,
// broadcast per-edge via __shfl (ds_bpermute). degmax = max over both halves
// (shfl_xor 32) keeps the window/group loops wave-uniform -> full exec for
// every shfl. Per-edge contributions masked by (w+g+j) < deg.
template <bool RELU>
__global__ __launch_bounds__(256) void gather128(const int* __restrict__ rowptr,
                                                 const unsigned short* __restrict__ srow,
                                                 const unsigned int* __restrict__ G,  // bf16x2
                                                 const float* __restrict__ dinv,
                                                 const float* __restrict__ bias,
                                                 unsigned int* __restrict__ H2,  // bf16x2 out
                                                 int N, int E) {
    int tid = blockIdx.x * 256 + (int)threadIdx.x;
    int node = tid >> 5;           // half-wave per node
    int lane = threadIdx.x & 63;
    int l32 = lane & 31;
    bool valid = node < N;
    int nc = valid ? node : (N - 1);   // clamped for safe addressing
    int beg = rowptr[nc];
    int end = rowptr[nc + 1];
    int deg = valid ? (end - beg) : 0;
    float dn = dinv[nc];

    // self-loop (x dinv[n]); row = 64 uints = 32 uint2
    uint2 s0 = ((const uint2*)G)[(size_t)nc * 32 + l32];
    float2 p0 = bfpair(s0.x), p1 = bfpair(s0.y);
    float ax = p0.x * dn, ay = p0.y * dn, az = p1.x * dn, aw = p1.y * dn;

    int degmax = max(deg, __shfl_xor(deg, 32));  // wave-uniform

    for (int w = 0; w < degmax; w += 32) {
        // one lane-indexed load covers 32 edge row-ids for this half
        int li = w + l32;
        li = (li < deg) ? li : (deg > 0 ? deg - 1 : 0);
        li += beg;
        li = (li < E) ? li : (E - 1);          // deg==0 node at array end
        int rv = (int)srow[li];
        float dv = dinv[rv];                   // pre-gather source dinv
        int lim = degmax - w;                  // uniform
        for (int g = 0; g < 32 && g < lim; g += 8) {
            uint2 u[8];
            float dr[8];
#pragma unroll
            for (int j = 0; j < 8; ++j) {
                int src = (lane & 32) | (g + j);    // broadcast within own half
                int r = __shfl(rv, src);
                dr[j] = __shfl(dv, src);
                u[j] = ((const uint2*)G)[(size_t)r * 32 + l32];
            }
            float sx = 0.f, sy = 0.f, sz = 0.f, sw = 0.f;
#pragma unroll
            for (int j = 0; j < 8; ++j) {
                bool ok = (w + g + j) < deg;
                unsigned int ux = ok ? u[j].x : 0u;
                unsigned int uy = ok ? u[j].y : 0u;
                float2 v0 = bfpair(ux), v1 = bfpair(uy);
                sx = fmaf(dr[j], v0.x, sx);
                sy = fmaf(dr[j], v0.y, sy);
                sz = fmaf(dr[j], v1.x, sz);
                sw = fmaf(dr[j], v1.y, sw);
            }
            ax += sx; ay += sy; az += sz; aw += sw;
        }
    }
    if (!valid) return;
    float4 bv = ((const float4*)bias)[l32];
    float ox = ax * dn + bv.x;
    float oy = ay * dn + bv.y;
    float oz = az * dn + bv.z;
    float ow = aw * dn + bv.w;
    if (RELU) {
        ox = fmaxf(ox, 0.f); oy = fmaxf(oy, 0.f);
        oz = fmaxf(oz, 0.f); ow = fmaxf(ow, 0.f);
    }
    unsigned long long pv =
        ((unsigned long long)packbf(oz, ow) << 32) | (unsigned long long)packbf(ox, oy);
    __builtin_nontemporal_store(pv, (unsigned long long*)H2 + (size_t)nc * 32 + l32);
}

// F=64 (R15): QUARTER-wave per node (16 lanes x 8B = 128B row) -> one row-load
// retires 4 edges. Same window/broadcast scheme; g2 pre-scaled by source dinv
// so no per-edge dinv needed. fp32 nt out.
template <bool RELU>
__global__ __launch_bounds__(256) void gather64(const int* __restrict__ rowptr,
                                                const unsigned short* __restrict__ srow,
                                                const unsigned int* __restrict__ G,  // bf16x2
                                                const float* __restrict__ dinv,
                                                const float* __restrict__ bias,
                                                float* __restrict__ O, int N, int E) {
    int tid = blockIdx.x * 256 + (int)threadIdx.x;
    int node = tid >> 4;          // quarter-wave per node
    int lane = threadIdx.x & 63;
    int l16 = lane & 15;
    bool valid = node < N;
    int nc = valid ? node : (N - 1);
    int beg = rowptr[nc];
    int end = rowptr[nc + 1];
    int deg = valid ? (end - beg) : 0;

    // self-loop; row = 32 uints = 16 uint2
    uint2 s0 = ((const uint2*)G)[(size_t)nc * 16 + l16];
    float2 p0 = bfpair(s0.x), p1 = bfpair(s0.y);
    float ax = p0.x, ay = p0.y, az = p1.x, aw = p1.y;

    int dm = max(deg, __shfl_xor(deg, 16));
    dm = max(dm, __shfl_xor(dm, 32));   // wave-uniform over 4 quarters

    for (int w = 0; w < dm; w += 16) {
        int li = w + l16;
        li = (li < deg) ? li : (deg > 0 ? deg - 1 : 0);
        li += beg;
        li = (li < E) ? li : (E - 1);
        int rv = (int)srow[li];
        int lim = dm - w;
        for (int g = 0; g < 16 && g < lim; g += 8) {
            uint2 u[8];
#pragma unroll
            for (int j = 0; j < 8; ++j) {
                int src = (lane & 48) | (g + j);    // broadcast within own quarter
                int r = __shfl(rv, src);
                u[j] = ((const uint2*)G)[(size_t)r * 16 + l16];
            }
            float sx = 0.f, sy = 0.f, sz = 0.f, sw = 0.f;
#pragma unroll
            for (int j = 0; j < 8; ++j) {
                bool ok = (w + g + j) < deg;
                unsigned int ux = ok ? u[j].x : 0u;
                unsigned int uy = ok ? u[j].y : 0u;
                float2 v0 = bfpair(ux), v1 = bfpair(uy);
                sx += v0.x; sy += v0.y; sz += v1.x; sw += v1.y;
            }
            ax += sx; ay += sy; az += sz; aw += sw;
        }
    }
    if (!valid) return;
    float s = dinv[nc];
    float4 bv = ((const float4*)bias)[l16];
    float ox = ax * s + bv.x;
    float oy = ay * s + bv.y;
    float oz = az * s + bv.z;
    float ow = aw * s + bv.w;
    if (RELU) {
        ox = fmaxf(ox, 0.f); oy = fmaxf(oy, 0.f);
        oz = fmaxf(oz, 0.f); ow = fmaxf(ow, 0.f);
    }
    float4v o = {ox, oy, oz, ow};
    __builtin_nontemporal_store(o, (float4v*)O + (size_t)nc * 16 + l16);
}

extern "C" void kernel_launch(void* const* d_in, const int* in_sizes, int n_in,
                              void* d_out, int out_size, void* d_ws, size_t ws_size,
                              hipStream_t stream) {
    const float* x  = (const float*)d_in[0];
    const int*   ei = (const int*)d_in[1];   // int32
    const float* W1 = (const float*)d_in[2];
    const float* b1 = (const float*)d_in[3];
    const float* W2 = (const float*)d_in[4];
    const float* b2 = (const float*)d_in[5];
    float* out = (float*)d_out;

    int N = in_sizes[0] / 128;
    int E = in_sizes[1] / 2;
    const int* row = ei;       // edge_index[0]
    const int* col = ei + E;   // edge_index[1]

    // Workspace layout (all regions written before read each call)
    char* ws = (char*)d_ws;
    float* dinv   = (float*)(ws + 0x000000);             // 200 KB
    int*   rowptr = (int*)  (ws + 0x080000);             // 200 KB + 4
    int*   gcur   = (int*)  (ws + 0x0F9000);             // 1 KB
    unsigned short* srow = (unsigned short*)(ws + 0x100000);   // 1.6 MB
    unsigned short* g1 = (unsigned short*)(ws + 0x440000);     // 12.8 MB
    unsigned short* wth1 = (unsigned short*)(ws + 0x10C0000);  // 32 KB
    unsigned short* wtl1 = (unsigned short*)(ws + 0x10D0000);  // 32 KB
    unsigned short* wth2 = (unsigned short*)(ws + 0x10E0000);  // 16 KB
    unsigned short* wtl2 = (unsigned short*)(ws + 0x10F0000);  // 16 KB
    unsigned short* h2 = (unsigned short*)(ws + 0x1200000);    // 12.8 MB (bf16)
    unsigned short* g2 = (unsigned short*)(ws + 0x2C00000);    // 6.4 MB
    // Packed slack bucket buffer (256 x BCAP uints = 6.29 MB) overlaps h2's
    // region: consumed by csr_and_gemm1 before gather128 first writes h2.
    unsigned int* bpack = (unsigned int*)(ws + 0x1200000);     // 6.29 MB

    int NB_BKT  = (E + CHUNK - 1) / CHUNK;   // 391
    int NBUCKET = (N + 255) / 256;           // 196
    int NB_GEMM1 = (N + 63) / 64;            // 782
    int NB_SETUP = 96;                       // 24576 transpose elems / 256

    // ---- gcur zero + merged scatter/setup + merged CSR/GEMM1 ----
    hipMemsetAsync(gcur, 0, 256 * sizeof(int), stream);
    scatter_setup<<<NB_BKT + NB_SETUP, 256, 0, stream>>>(
        row, col, gcur, bpack, E, NB_BKT, W1, wth1, wtl1, W2, wth2, wtl2);
    csr_and_gemm1<<<NBUCKET + NB_GEMM1, 256, 0, stream>>>(
        bpack, gcur, rowptr, dinv, srow, N, E, NBUCKET, x, wth1, wtl1, g1);

    int nb;
    // ---- layer-1 gather (dinv folded in), half-wave per node ----
    nb = (N + 7) / 8;
    gather128<true><<<nb, 256, 0, stream>>>(rowptr, srow, (const unsigned int*)g1,
                                            dinv, b1, (unsigned int*)h2, N, E);

    // ---- layer 2 (F=64, no relu) ----
    nb = (N + 63) / 64;
    gemm_mfma2<<<nb, 256, 0, stream>>>(h2, wth2, wtl2, dinv, g2, N);
    nb = (N + 15) / 16;   // quarter-wave per node
    gather64<false><<<nb, 256, 0, stream>>>(rowptr, srow, (const unsigned int*)g2,
                                            dinv, b2, out, N, E);
}